// Round 1
// baseline (317.468 us; speedup 1.0000x reference)
//
#include <hip/hip_runtime.h>
#include <math.h>

#define H_FM 200
#define W_FM 304
#define C_FM 256
#define PIXB (C_FM * 4)          // 1024 bytes per feature-map pixel
#define CROP 14
#define PH 7
#define NPOS 49                  // 7*7 output positions
#define NSAMP (NPOS * 4)         // 196 (position, sample) pairs per ROI

typedef float floatx4 __attribute__((ext_vector_type(4)));

// One block = one ROI, all 256 channels.
//
// Phase 1 (once per block): threads 0..195 each compute the geometry of one
// (position p, sample s) pair -> LDS:
//   gO[t] = { byte_off(tap00), dxB (0|1024), dyB (0|W*1024), pad }
//   gW[t] = { w00, w01, w10, w11 }   bilinear weights, zeroed if !valid
// Validity therefore costs ZERO in the hot loop (dot with zero weights == 0,
// matching the reference's jnp.where(valid, val, 0)).
//
// Phase 2: wave = one position at a time, lane = channel-quad (64 lanes x 16B
// = all 256 ch). Each tap load is a fully coalesced 1KB wave load from the
// ORIGINAL [H,W,256] layout -> no repack kernel, no workspace. The 4 samples
// of the 2x2 pooling window are accumulated with in-register fmaxf -> no
// cross-lane shuffles.
__global__ __launch_bounds__(256) void roi_pool_kernel(
    const float* __restrict__ fm,          // [200,304,256] f32
    const float* __restrict__ proposals,   // [N,4] (x1,y1,x2,y2) image coords
    const int*   __restrict__ image_shape, // [2] (H_img, W_img)
    float*       __restrict__ out,         // [N,7,7,256] f32
    int N)
{
    __shared__ uint4  gO[NSAMP];
    __shared__ float4 gW[NSAMP];

    const int n   = blockIdx.x;
    const int tid = threadIdx.x;

    if (tid < NSAMP) {
        const int s  = tid & 3;
        const int p  = tid >> 2;
        const int py = p / PH;
        const int px = p - py * PH;
        const int a  = s >> 1;          // y sub-offset in 2x2 window
        const int b  = s & 1;           // x sub-offset

        const float himg = (float)image_shape[0];
        const float wimg = (float)image_shape[1];

        const float bx1 = proposals[n * 4 + 0] / wimg;
        const float by1 = proposals[n * 4 + 1] / himg;
        const float bx2 = proposals[n * 4 + 2] / wimg;
        const float by2 = proposals[n * 4 + 3] / himg;

        const float Hm1 = (float)(H_FM - 1);
        const float Wm1 = (float)(W_FM - 1);

        // matches reference: ys = y1*(H-1) + i * ((y2-y1)*(H-1)/(crop-1))
        const float ystep = (by2 - by1) * Hm1 / (float)(CROP - 1);
        const float xstep = (bx2 - bx1) * Wm1 / (float)(CROP - 1);
        const float ys = by1 * Hm1 + (float)(2 * py + a) * ystep;
        const float xs = bx1 * Wm1 + (float)(2 * px + b) * xstep;

        const float y0f = floorf(ys);
        const float x0f = floorf(xs);
        const float ly  = ys - y0f;
        const float lx  = xs - x0f;

        int y0 = min(max((int)y0f, 0), H_FM - 1);
        int x0 = min(max((int)x0f, 0), W_FM - 1);
        const int dy = min(y0 + 1, H_FM - 1) - y0;   // 0 or 1
        const int dx = min(x0 + 1, W_FM - 1) - x0;   // 0 or 1

        const bool valid = (ys >= 0.0f) && (ys <= Hm1) &&
                           (xs >= 0.0f) && (xs <= Wm1);
        const float vf   = valid ? 1.0f : 0.0f;
        const float omlx = 1.0f - lx;
        const float omly = 1.0f - ly;

        float4 w;
        w.x = omlx * omly * vf;   // w00
        w.y = lx   * omly * vf;   // w01
        w.z = omlx * ly   * vf;   // w10
        w.w = lx   * ly   * vf;   // w11

        uint4 o;
        o.x = (uint32_t)(y0 * W_FM + x0) * PIXB;
        o.y = (uint32_t)dx * PIXB;
        o.z = (uint32_t)(dy * W_FM) * PIXB;
        o.w = 0u;

        gO[tid] = o;
        gW[tid] = w;
    }
    __syncthreads();

    const int wave = tid >> 6;
    const int lane = tid & 63;
    const uint32_t laneB = (uint32_t)lane * 16u;   // 16B per lane = 4 channels
    const char* fmB  = (const char*)fm;
    char*       outB = (char*)out + (size_t)n * (NPOS * PIXB);

    // contiguous position ranges per wave: 12,12,12,13 (spatial locality in L1)
    const int pbeg = (wave * NPOS) >> 2;
    const int pend = ((wave + 1) * NPOS) >> 2;

    for (int p = pbeg; p < pend; ++p) {
        float4 m;
        #pragma unroll
        for (int s = 0; s < 4; ++s) {
            const uint4  o = gO[p * 4 + s];   // broadcast ds_read_b128
            const float4 w = gW[p * 4 + s];

            const uint32_t o00 = o.x + laneB;
            const uint32_t o01 = o00 + o.y;
            const uint32_t o10 = o00 + o.z;
            const uint32_t o11 = o10 + o.y;

            const float4 t00 = *(const float4*)(fmB + o00);
            const float4 t01 = *(const float4*)(fmB + o01);
            const float4 t10 = *(const float4*)(fmB + o10);
            const float4 t11 = *(const float4*)(fmB + o11);

            float4 v;
            v.x = fmaf(t00.x, w.x, fmaf(t01.x, w.y, fmaf(t10.x, w.z, t11.x * w.w)));
            v.y = fmaf(t00.y, w.x, fmaf(t01.y, w.y, fmaf(t10.y, w.z, t11.y * w.w)));
            v.z = fmaf(t00.z, w.x, fmaf(t01.z, w.y, fmaf(t10.z, w.z, t11.z * w.w)));
            v.w = fmaf(t00.w, w.x, fmaf(t01.w, w.y, fmaf(t10.w, w.z, t11.w * w.w)));

            if (s == 0) {
                m = v;
            } else {
                m.x = fmaxf(m.x, v.x);
                m.y = fmaxf(m.y, v.y);
                m.z = fmaxf(m.z, v.z);
                m.w = fmaxf(m.w, v.w);
            }
        }

        floatx4 mv;
        mv.x = m.x; mv.y = m.y; mv.z = m.z; mv.w = m.w;
        // non-temporal: keep the 100MB output stream from evicting fm in L2
        __builtin_nontemporal_store(mv,
            (floatx4*)(outB + (uint32_t)p * PIXB + laneB));
    }
}

extern "C" void kernel_launch(void* const* d_in, const int* in_sizes, int n_in,
                              void* d_out, int out_size, void* d_ws, size_t ws_size,
                              hipStream_t stream) {
    (void)d_ws; (void)ws_size; (void)n_in; (void)out_size;

    const float* fm        = (const float*)d_in[0];  // [1,200,304,256] f32
    const float* proposals = (const float*)d_in[1];  // [N,4] f32
    const int*   imshape   = (const int*)d_in[2];    // [2] i32
    float* out = (float*)d_out;                      // [N,7,7,256] f32

    const int N = in_sizes[1] / 4;                   // 2000

    roi_pool_kernel<<<N, 256, 0, stream>>>(fm, proposals, imshape, out, N);
}

// Round 2
// 215.535 us; speedup vs baseline: 1.4729x; 1.4729x over previous
//
#include <hip/hip_runtime.h>
#include <math.h>

#define H_FM 200
#define W_FM 304
#define C_FM 256
#define NPIX (H_FM * W_FM)           // 60800
#define CROP 14
#define PH 7
#define NPOS 49                       // 7*7
#define NSAMP (NPOS * 4)              // 196 (position, sample) pairs
#define SLABS 16
#define SLAB_C 16                     // channels per slab
#define SLAB_ELEMS (NPIX * SLAB_C)    // 972800 floats = 3.89 MB dense per slab
#define SPIXB (SLAB_C * 4)            // 64 B per pixel within a slab
#define PIXB (C_FM * 4)               // 1024 B per pixel original layout

typedef float floatx4 __attribute__((ext_vector_type(4)));

// ---------------------------------------------------------------------------
// Repack [H,W,256] -> 16 dense slabs [NPIX][16], LDS-tiled so BOTH sides are
// dense. Block = 16 pixels: read 16KB fully coalesced -> LDS -> each slab
// receives a 1KB contiguous chunk (per store instruction: 16 lanes x 16B =
// 256B contiguous per slab). Old repack wrote 16 scattered 64B chunks per
// wave (~1 TB/s, ~125us); this should run at ~4-5 TB/s (~25us).
// ---------------------------------------------------------------------------
#define TP 16  // pixels per block
__global__ __launch_bounds__(256) void repack_kernel(
    const float* __restrict__ fm,      // [NPIX, 256]
    float*       __restrict__ slabbed) // [16][NPIX][16]
{
    __shared__ float lds[TP][C_FM + 4];   // +4: rows stay 16B-aligned, banks rotate
    const int tid = threadIdx.x;
    const int p0  = blockIdx.x * TP;

    const float4* src = (const float4*)(fm + (size_t)p0 * C_FM);
    #pragma unroll
    for (int i = 0; i < 4; ++i) {
        const int idx = i * 256 + tid;     // float4 index within 16-pixel tile
        const float4 v = src[idx];
        const int pix = idx >> 6;          // 64 float4 per pixel
        const int c4  = idx & 63;
        *(float4*)&lds[pix][c4 * 4] = v;
    }
    __syncthreads();

    const int s = tid >> 4;                // slab 0..15
    const int j = tid & 15;
    float* dst = slabbed + (size_t)s * SLAB_ELEMS + (size_t)p0 * SLAB_C;
    #pragma unroll
    for (int k = 0; k < 4; ++k) {
        const int m   = k * 16 + j;        // float4 idx within [16pix][16ch] stream
        const int pix = m >> 2;
        const int cq  = m & 3;
        const float4 v = *(const float4*)&lds[pix][s * SLAB_C + cq * 4];
        *(float4*)(dst + m * 4) = v;       // lanes j contiguous: 256B/instr/slab
    }
}

// ---------------------------------------------------------------------------
// Pool kernel: block = (ROI n, slab). XCD pinning (xcd = bid & 7) keeps each
// XCD streaming ONE dense 3.9MB slab (L2-resident) for all N ROIs -> fixes
// R1's 627MB over-fetch while keeping R1's cheap hot loop:
//   Phase 1: threads 0..195 compute geometry of one (position,sample) into
//            LDS (skewed index: kills the 8-way bank conflict of stride-16B
//            entries read by 16 lane-groups). Weights pre-zeroed if !valid.
//   Phase 2: lane = pos16*4 + quad (16 positions x 4 channel-quads per wave);
//            4 samples accumulated with in-register fmaxf -> NO shuffles;
//            bilinear = 4 FMAs per channel (weighted sum).
// ---------------------------------------------------------------------------
__global__ __launch_bounds__(256) void roi_pool_slab_kernel(
    const float* __restrict__ slabbed,     // [16][NPIX][16]
    const float* __restrict__ proposals,   // [N,4] (x1,y1,x2,y2) image coords
    const int*   __restrict__ image_shape, // [2] (H_img, W_img)
    float*       __restrict__ out,         // [N,7,7,256]
    int N)
{
    __shared__ uint2  gOD[224];   // {byte_off(tap00), dxB | dyB<<16}, skew-indexed
    __shared__ float4 gW[224];    // bilinear weights, zeroed when invalid

    const int bid   = blockIdx.x;
    const int xcd   = bid & 7;
    const int jj    = bid >> 3;        // 0 .. 2N-1
    const int phase = jj / N;          // 0 or 1
    const int n     = jj - phase * N;  // ROI index
    const int slab  = phase * 8 + xcd; // 0..15

    const int tid = threadIdx.x;

    if (tid < NSAMP) {
        const int s  = tid & 3;
        const int p  = tid >> 2;
        const int py = p / PH;
        const int px = p - py * PH;
        const int a  = s >> 1;          // y sub-offset in 2x2 window
        const int b  = s & 1;           // x sub-offset

        const float himg = (float)image_shape[0];
        const float wimg = (float)image_shape[1];

        const float bx1 = proposals[n * 4 + 0] / wimg;
        const float by1 = proposals[n * 4 + 1] / himg;
        const float bx2 = proposals[n * 4 + 2] / wimg;
        const float by2 = proposals[n * 4 + 3] / himg;

        const float Hm1 = (float)(H_FM - 1);
        const float Wm1 = (float)(W_FM - 1);

        // matches reference: ys = y1*(H-1) + i * ((y2-y1)*(H-1)/(crop-1))
        const float ystep = (by2 - by1) * Hm1 / (float)(CROP - 1);
        const float xstep = (bx2 - bx1) * Wm1 / (float)(CROP - 1);
        const float ys = by1 * Hm1 + (float)(2 * py + a) * ystep;
        const float xs = bx1 * Wm1 + (float)(2 * px + b) * xstep;

        const float y0f = floorf(ys);
        const float x0f = floorf(xs);
        const float ly  = ys - y0f;
        const float lx  = xs - x0f;

        int y0 = min(max((int)y0f, 0), H_FM - 1);
        int x0 = min(max((int)x0f, 0), W_FM - 1);
        const int dy = min(y0 + 1, H_FM - 1) - y0;   // 0 or 1
        const int dx = min(x0 + 1, W_FM - 1) - x0;   // 0 or 1

        const bool valid = (ys >= 0.0f) && (ys <= Hm1) &&
                           (xs >= 0.0f) && (xs <= Wm1);
        const float vf   = valid ? 1.0f : 0.0f;
        const float omlx = 1.0f - lx;
        const float omly = 1.0f - ly;

        float4 w;
        w.x = omlx * omly * vf;   // w00
        w.y = lx   * omly * vf;   // w01
        w.z = omlx * ly   * vf;   // w10
        w.w = lx   * ly   * vf;   // w11

        uint2 od;
        od.x = (uint32_t)(y0 * W_FM + x0) * SPIXB;
        od.y = (uint32_t)(dx * SPIXB) | ((uint32_t)(dy * W_FM * SPIXB) << 16);

        const int esk = tid + (tid >> 3);   // skew: entry e -> e + e/8
        gOD[esk] = od;
        gW[esk]  = w;
    }
    __syncthreads();

    const int wave = tid >> 6;
    const int lane = tid & 63;
    const int p    = wave * 16 + (lane >> 2);   // output position 0..63
    const int q    = lane & 3;                  // channel quad within slab
    const int pa   = min(p, NPOS - 1);          // clamp: wave 3 mostly idles

    const char* base = (const char*)slabbed + (size_t)slab * (SLAB_ELEMS * sizeof(float));
    const uint32_t qB = (uint32_t)q * 16u;

    float4 m;
    #pragma unroll
    for (int s = 0; s < 4; ++s) {
        const int e   = pa * 4 + s;
        const int esk = e + (e >> 3);
        const uint2  od = gOD[esk];
        const float4 w  = gW[esk];

        const uint32_t o00 = od.x + qB;
        const uint32_t dxB = od.y & 0xffffu;
        const uint32_t dyB = od.y >> 16;

        const float4 t00 = *(const float4*)(base + o00);
        const float4 t01 = *(const float4*)(base + o00 + dxB);
        const float4 t10 = *(const float4*)(base + o00 + dyB);
        const float4 t11 = *(const float4*)(base + o00 + dxB + dyB);

        float4 v;
        v.x = fmaf(t00.x, w.x, fmaf(t01.x, w.y, fmaf(t10.x, w.z, t11.x * w.w)));
        v.y = fmaf(t00.y, w.x, fmaf(t01.y, w.y, fmaf(t10.y, w.z, t11.y * w.w)));
        v.z = fmaf(t00.z, w.x, fmaf(t01.z, w.y, fmaf(t10.z, w.z, t11.z * w.w)));
        v.w = fmaf(t00.w, w.x, fmaf(t01.w, w.y, fmaf(t10.w, w.z, t11.w * w.w)));

        if (s == 0) {
            m = v;
        } else {
            m.x = fmaxf(m.x, v.x);
            m.y = fmaxf(m.y, v.y);
            m.z = fmaxf(m.z, v.z);
            m.w = fmaxf(m.w, v.w);
        }
    }

    if (p < NPOS) {
        floatx4 mv;
        mv.x = m.x; mv.y = m.y; mv.z = m.z; mv.w = m.w;
        // non-temporal: keep the 98MB output stream from evicting the slab in L2
        __builtin_nontemporal_store(mv,
            (floatx4*)(out + ((size_t)n * NPOS + p) * C_FM + slab * SLAB_C + q * 4));
    }
}

// ---------------------------------------------------------------------------
// Fallback (no workspace): R1 all-channel kernel — correct, no ws needed.
// ---------------------------------------------------------------------------
__global__ __launch_bounds__(256) void roi_pool_direct_kernel(
    const float* __restrict__ fm,
    const float* __restrict__ proposals,
    const int*   __restrict__ image_shape,
    float*       __restrict__ out,
    int N)
{
    __shared__ uint4  gO[NSAMP];
    __shared__ float4 gWf[NSAMP];

    const int n   = blockIdx.x;
    const int tid = threadIdx.x;

    if (tid < NSAMP) {
        const int s  = tid & 3;
        const int p  = tid >> 2;
        const int py = p / PH;
        const int px = p - py * PH;
        const int a  = s >> 1;
        const int b  = s & 1;

        const float himg = (float)image_shape[0];
        const float wimg = (float)image_shape[1];
        const float bx1 = proposals[n * 4 + 0] / wimg;
        const float by1 = proposals[n * 4 + 1] / himg;
        const float bx2 = proposals[n * 4 + 2] / wimg;
        const float by2 = proposals[n * 4 + 3] / himg;

        const float Hm1 = (float)(H_FM - 1);
        const float Wm1 = (float)(W_FM - 1);
        const float ystep = (by2 - by1) * Hm1 / (float)(CROP - 1);
        const float xstep = (bx2 - bx1) * Wm1 / (float)(CROP - 1);
        const float ys = by1 * Hm1 + (float)(2 * py + a) * ystep;
        const float xs = bx1 * Wm1 + (float)(2 * px + b) * xstep;

        const float y0f = floorf(ys);
        const float x0f = floorf(xs);
        const float ly  = ys - y0f;
        const float lx  = xs - x0f;
        int y0 = min(max((int)y0f, 0), H_FM - 1);
        int x0 = min(max((int)x0f, 0), W_FM - 1);
        const int dy = min(y0 + 1, H_FM - 1) - y0;
        const int dx = min(x0 + 1, W_FM - 1) - x0;
        const bool valid = (ys >= 0.0f) && (ys <= Hm1) &&
                           (xs >= 0.0f) && (xs <= Wm1);
        const float vf   = valid ? 1.0f : 0.0f;
        const float omlx = 1.0f - lx;
        const float omly = 1.0f - ly;

        float4 w;
        w.x = omlx * omly * vf;
        w.y = lx   * omly * vf;
        w.z = omlx * ly   * vf;
        w.w = lx   * ly   * vf;

        uint4 o;
        o.x = (uint32_t)(y0 * W_FM + x0) * PIXB;
        o.y = (uint32_t)dx * PIXB;
        o.z = (uint32_t)(dy * W_FM) * PIXB;
        o.w = 0u;
        gO[tid]  = o;
        gWf[tid] = w;
    }
    __syncthreads();

    const int wave = tid >> 6;
    const int lane = tid & 63;
    const uint32_t laneB = (uint32_t)lane * 16u;
    const char* fmB  = (const char*)fm;
    char*       outB = (char*)out + (size_t)n * (NPOS * PIXB);

    const int pbeg = (wave * NPOS) >> 2;
    const int pend = ((wave + 1) * NPOS) >> 2;

    for (int p = pbeg; p < pend; ++p) {
        float4 m;
        #pragma unroll
        for (int s = 0; s < 4; ++s) {
            const uint4  o = gO[p * 4 + s];
            const float4 w = gWf[p * 4 + s];
            const uint32_t o00 = o.x + laneB;
            const float4 t00 = *(const float4*)(fmB + o00);
            const float4 t01 = *(const float4*)(fmB + o00 + o.y);
            const float4 t10 = *(const float4*)(fmB + o00 + o.z);
            const float4 t11 = *(const float4*)(fmB + o00 + o.y + o.z);
            float4 v;
            v.x = fmaf(t00.x, w.x, fmaf(t01.x, w.y, fmaf(t10.x, w.z, t11.x * w.w)));
            v.y = fmaf(t00.y, w.x, fmaf(t01.y, w.y, fmaf(t10.y, w.z, t11.y * w.w)));
            v.z = fmaf(t00.z, w.x, fmaf(t01.z, w.y, fmaf(t10.z, w.z, t11.z * w.w)));
            v.w = fmaf(t00.w, w.x, fmaf(t01.w, w.y, fmaf(t10.w, w.z, t11.w * w.w)));
            if (s == 0) { m = v; }
            else {
                m.x = fmaxf(m.x, v.x); m.y = fmaxf(m.y, v.y);
                m.z = fmaxf(m.z, v.z); m.w = fmaxf(m.w, v.w);
            }
        }
        floatx4 mv;
        mv.x = m.x; mv.y = m.y; mv.z = m.z; mv.w = m.w;
        __builtin_nontemporal_store(mv,
            (floatx4*)(outB + (uint32_t)p * PIXB + laneB));
    }
}

extern "C" void kernel_launch(void* const* d_in, const int* in_sizes, int n_in,
                              void* d_out, int out_size, void* d_ws, size_t ws_size,
                              hipStream_t stream) {
    (void)n_in; (void)out_size;

    const float* fm        = (const float*)d_in[0];  // [1,200,304,256] f32
    const float* proposals = (const float*)d_in[1];  // [N,4] f32
    const int*   imshape   = (const int*)d_in[2];    // [2] i32
    float* out = (float*)d_out;                      // [N,7,7,256] f32

    const int N = in_sizes[1] / 4;                   // 2000
    const size_t needed = (size_t)SLABS * SLAB_ELEMS * sizeof(float); // 62.3 MB

    if (ws_size >= needed) {
        repack_kernel<<<NPIX / TP, 256, 0, stream>>>(fm, (float*)d_ws);
        roi_pool_slab_kernel<<<SLABS * N, 256, 0, stream>>>(
            (const float*)d_ws, proposals, imshape, out, N);
    } else {
        roi_pool_direct_kernel<<<N, 256, 0, stream>>>(
            fm, proposals, imshape, out, N);
    }
}